// Round 3
// baseline (443.145 us; speedup 1.0000x reference)
//
#include <hip/hip_runtime.h>
#include <hip/hip_bf16.h>

// Problem constants (from reference)
#define NE 8            // experts
#define NH 1024         // hidden
#define NF 2048         // ffn
#define NT_TOK 4096     // tokens = B*S
#define CAP 640         // ceil(1.25 * 4096 / 8) -- capacity semantics
#define CAPP 768        // padded rows per expert (multiple of 256)

typedef __bf16 bf16x8 __attribute__((ext_vector_type(8)));
typedef float f32x4 __attribute__((ext_vector_type(4)));

__device__ __forceinline__ ushort f2bf(float f) {
    union { float f; unsigned u; } v; v.f = f;
    unsigned r = (v.u + 0x7FFFu + ((v.u >> 16) & 1u)) >> 16;
    return (ushort)r;
}

// async global->LDS, 16B per lane, dest = wave-uniform base + lane*16
__device__ __forceinline__ void glds16(const ushort* g, ushort* l) {
    __builtin_amdgcn_global_load_lds((const __attribute__((address_space(1))) void*)g,
                                     (__attribute__((address_space(3))) void*)l,
                                     16, 0, 0);
}

#define MFMA_BF16 __builtin_amdgcn_mfma_f32_16x16x32_bf16

// ---------------------------------------------------------------------------
// K0: convert+transpose  in fp32 [E][R][C] -> out bf16 [E][C][R]
// No LDS: coalesced scalar column reads, packed uint4 writes.
// block 256 thr: tile = 64 cols x 128 rows; thread: 1 col x 32 rows.
// ---------------------------------------------------------------------------
__global__ __launch_bounds__(256) void k_conv_t(
    const float* __restrict__ in, ushort* __restrict__ out, int R, int C)
{
    int e = blockIdx.z;
    int c  = blockIdx.x * 64 + (threadIdx.x & 63);
    int rb = blockIdx.y * 128 + (threadIdx.x >> 6) * 32;
    in  += (size_t)e * R * C;
    out += (size_t)e * R * C;
    float v[32];
    #pragma unroll
    for (int j = 0; j < 32; ++j) v[j] = in[(size_t)(rb + j) * C + c];
    #pragma unroll
    for (int q = 0; q < 4; ++q) {
        union { ushort sh[8]; uint4 u; } p;
        #pragma unroll
        for (int j = 0; j < 8; ++j) p.sh[j] = f2bf(v[q * 8 + j]);
        *(uint4*)(out + (size_t)c * R + rb + q * 8) = p.u;
    }
}

// ---------------------------------------------------------------------------
// K1: per-token LayerNorm (fp32) + router logits + softmax + top-2
// ---------------------------------------------------------------------------
__global__ __launch_bounds__(256) void k_ln_router(
    const float* __restrict__ x, const float* __restrict__ rw,
    const float* __restrict__ gamma, const float* __restrict__ beta,
    ushort* __restrict__ tok_bf, int* __restrict__ idx, float* __restrict__ wts)
{
    int t = blockIdx.x, tid = threadIdx.x;
    int lane = tid & 63, wid = tid >> 6;
    const float* xp = x + (size_t)t * NH;

    float4 v = *(const float4*)(xp + tid * 4);
    float xs[4] = {v.x, v.y, v.z, v.w};
    float s = xs[0] + xs[1] + xs[2] + xs[3];
    float q = xs[0]*xs[0] + xs[1]*xs[1] + xs[2]*xs[2] + xs[3]*xs[3];

    __shared__ float rs[4], rq[4], rl[4][8];
    #pragma unroll
    for (int o = 32; o; o >>= 1) { s += __shfl_xor(s, o); q += __shfl_xor(q, o); }
    if (lane == 0) { rs[wid] = s; rq[wid] = q; }
    __syncthreads();
    float S = rs[0] + rs[1] + rs[2] + rs[3];
    float Q = rq[0] + rq[1] + rq[2] + rq[3];
    float mean = S * (1.0f / NH);
    float var  = Q * (1.0f / NH) - mean * mean;
    float rstd = 1.0f / sqrtf(var + 1e-5f);

    float le[8] = {0,0,0,0,0,0,0,0};
    ushort tb[4];
    #pragma unroll
    for (int j = 0; j < 4; ++j) {
        int h = tid * 4 + j;
        float nh = (xs[j] - mean) * rstd * gamma[h] + beta[h];
        tb[j] = f2bf(nh);
        float4 r0 = *(const float4*)(rw + h * 8);
        float4 r1 = *(const float4*)(rw + h * 8 + 4);
        le[0] += nh * r0.x; le[1] += nh * r0.y; le[2] += nh * r0.z; le[3] += nh * r0.w;
        le[4] += nh * r1.x; le[5] += nh * r1.y; le[6] += nh * r1.z; le[7] += nh * r1.w;
    }
    union { ushort s2[4]; uint2 u2; } pk;
    pk.s2[0]=tb[0]; pk.s2[1]=tb[1]; pk.s2[2]=tb[2]; pk.s2[3]=tb[3];
    *(uint2*)(tok_bf + (size_t)t * NH + tid * 4) = pk.u2;

    #pragma unroll
    for (int o = 32; o; o >>= 1)
        #pragma unroll
        for (int e = 0; e < 8; ++e) le[e] += __shfl_xor(le[e], o);
    if (lane == 0)
        #pragma unroll
        for (int e = 0; e < 8; ++e) rl[wid][e] = le[e];
    __syncthreads();

    if (tid == 0) {
        float l[8];
        #pragma unroll
        for (int e = 0; e < 8; ++e) l[e] = rl[0][e] + rl[1][e] + rl[2][e] + rl[3][e];
        float mx = l[0];
        #pragma unroll
        for (int e = 1; e < 8; ++e) mx = fmaxf(mx, l[e]);
        float p[8], den = 0.f;
        #pragma unroll
        for (int e = 0; e < 8; ++e) { p[e] = expf(l[e] - mx); den += p[e]; }
        float rden = 1.0f / den;
        #pragma unroll
        for (int e = 0; e < 8; ++e) p[e] *= rden;
        int i0 = 0; float b0 = p[0];
        #pragma unroll
        for (int e = 1; e < 8; ++e) if (p[e] > b0) { b0 = p[e]; i0 = e; }
        int i1 = (i0 == 0) ? 1 : 0; float b1 = p[i1];
        #pragma unroll
        for (int e = 0; e < 8; ++e) if (e != i0 && p[e] > b1) { b1 = p[e]; i1 = e; }
        float sw = 1.0f / (b0 + b1);
        idx[2*t] = i0; idx[2*t+1] = i1;
        wts[2*t] = b0 * sw; wts[2*t+1] = b1 * sw;
    }
}

// ---------------------------------------------------------------------------
// K2: per-expert ordered compaction (stable by token index, capacity CAP)
// ---------------------------------------------------------------------------
__global__ __launch_bounds__(1024) void k_build_sel(
    const int* __restrict__ idx, int* __restrict__ sel)
{
    int e = blockIdx.x, tid = threadIdx.x;
    int lane = tid & 63, wid = tid >> 6;
    __shared__ int wsum[16], wpre[16], sbase;
    if (tid < CAPP) sel[e * CAPP + tid] = -1;
    if (tid == 0) sbase = 0;
    __syncthreads();

    for (int ch = 0; ch < NT_TOK / 1024; ++ch) {
        int t = ch * 1024 + tid;
        int m = (idx[2*t] == e || idx[2*t+1] == e) ? 1 : 0;
        int v = m;
        #pragma unroll
        for (int d = 1; d < 64; d <<= 1) {
            int u = __shfl_up(v, d);
            if (lane >= d) v += u;
        }
        if (lane == 63) wsum[wid] = v;
        __syncthreads();
        if (tid < 16) {
            int ws = wsum[tid], wv = ws;
            #pragma unroll
            for (int d = 1; d < 16; d <<= 1) {
                int u = __shfl_up(wv, d);
                if (tid >= d) wv += u;
            }
            wpre[tid] = wv - ws;
        }
        __syncthreads();
        int base0 = sbase;
        int slot = base0 + wpre[wid] + v - m;
        if (m && slot < CAP) sel[e * CAPP + slot] = t;
        __syncthreads();
        if (tid == 0) sbase = base0 + wpre[15] + wsum[15];
        __syncthreads();
    }
}

// ---------------------------------------------------------------------------
// K3: gather tokens into per-expert slot rows (zeros for invalid/pad slots)
// grid = NE*CAPP blocks
// ---------------------------------------------------------------------------
__global__ __launch_bounds__(256) void k_gather(
    const int* __restrict__ sel, const ushort* __restrict__ tok,
    ushort* __restrict__ xin)
{
    int sIdx = blockIdx.x;
    int tokid = sel[sIdx];
    uint2 v = make_uint2(0u, 0u);
    if (tokid >= 0)
        v = *(const uint2*)(tok + (size_t)tokid * NH + threadIdx.x * 4);
    *(uint2*)(xin + (size_t)sIdx * NH + threadIdx.x * 4) = v;
}

// ===========================================================================
// Pipelined grouped GEMMs: BK=32, 4 LDS slots, counted vmcnt (T4), row-pair
// XOR swizzle (T2, 2-way = free), setprio MFMA cluster (T5), raw s_barrier.
//
// LDS layout per operand slot: "LDS-row" = 128B holding TWO K-rows (a=2R, 2R+1)
//   element (row a, chunk lq of 8 bf16) stored at LDS-row a>>1,
//   16B-slot s = (((a&1)<<2)|lq) ^ ((a>>1)&7).
// Stage: glds16 linear dest; lane tid: R=tid>>3, s=tid&7, u=s^(R&7)
//   -> global row 2R+(u>>2), elem col (u&3)*8.  (involution: read==write swz)
// ===========================================================================

// ---------------------------------------------------------------------------
// GEMM1 fused: hb[e] = silu(xin@wgT^T)*(xin@wuT^T)   M=CAPP,Ng=Nu=128/blk,K=NH
// BM=256, BN=128 (gate)+128 (up), 8 waves (wm2 x wn4), wave out 128x32 per set
// ---------------------------------------------------------------------------
__global__ __launch_bounds__(512, 2) void k_gemm1(
    const ushort* __restrict__ xin, const ushort* __restrict__ wgT,
    const ushort* __restrict__ wuT, ushort* __restrict__ hb)
{
    __shared__ __align__(16) ushort As[4][8192];   // 64 KB: 256 rows x 32 k
    __shared__ __align__(16) ushort Bgs[4][4096];  // 32 KB: 128 rows x 32 k
    __shared__ __align__(16) ushort Bus[4][4096];  // 32 KB

    int e = blockIdx.z, mb = blockIdx.y, nb = blockIdx.x;
    const ushort* A  = xin + (size_t)e * CAPP * NH + (size_t)mb * 256 * NH;
    const ushort* Bg = wgT + (size_t)e * NF * NH + (size_t)nb * 128 * NH;
    const ushort* Bu = wuT + (size_t)e * NF * NH + (size_t)nb * 128 * NH;

    int tid = threadIdx.x, lane = tid & 63, wid = tid >> 6;
    int wm = wid >> 2, wn = wid & 3;        // wm 0..1, wn 0..3
    int lr = lane & 15, lq = lane >> 4;

    // staging source decomposition (inverse swizzle)
    int Rg = tid >> 3;                      // 0..63
    int ug = (tid & 7) ^ (Rg & 7);
    int sROW2 = ug >> 2;
    int sCOL  = (ug & 3) * 8;
    size_t aoffg0 = (size_t)(2 * Rg + sROW2) * NH + sCOL;          // j=0
    size_t aoffg1 = (size_t)(2 * (64 + Rg) + sROW2) * NH + sCOL;   // j=1
    size_t boffg  = (size_t)(2 * Rg + sROW2) * NH + sCOL;
    int aldsu0 = (wid * 8) * 64;            // ushort offsets, wave-uniform
    int aldsu1 = (64 + wid * 8) * 64;
    int bldsu  = wid * 512;

    // loop-invariant frag read offsets (ushort)
    int aoff[8], goff[2];
    #pragma unroll
    for (int m = 0; m < 8; ++m) {
        int a = wm * 128 + m * 16 + lr;
        int Rr = a >> 1;
        int sl = (((a & 1) << 2) | lq) ^ (Rr & 7);
        aoff[m] = Rr * 64 + sl * 8;
    }
    #pragma unroll
    for (int n = 0; n < 2; ++n) {
        int nn = wn * 32 + n * 16 + lr;
        int Rr = nn >> 1;
        int sl = (((nn & 1) << 2) | lq) ^ (Rr & 7);
        goff[n] = Rr * 64 + sl * 8;
    }

    f32x4 accg[8][2] = {}; f32x4 accu[8][2] = {};

    const int NT = NH / 32;   // 32 K-tiles

    #define STAGE1(t) do { int _sl = (t) & 3; int _k0 = (t) * 32;               \
        glds16(A  + aoffg0 + _k0, &As[_sl][aldsu0]);                            \
        glds16(A  + aoffg1 + _k0, &As[_sl][aldsu1]);                            \
        glds16(Bg + boffg  + _k0, &Bgs[_sl][bldsu]);                            \
        glds16(Bu + boffg  + _k0, &Bus[_sl][bldsu]); } while (0)

    STAGE1(0); STAGE1(1);
    asm volatile("s_waitcnt vmcnt(4)" ::: "memory");
    asm volatile("s_barrier" ::: "memory");

    for (int t = 0; t < NT; ++t) {
        int slot = t & 3;
        bool pf = (t + 2 < NT);
        if (pf) STAGE1(t + 2);
        const ushort* Ab = &As[slot][0];
        const ushort* Gb = &Bgs[slot][0];
        const ushort* Ub = &Bus[slot][0];
        bf16x8 af[8], bg[2], bu[2];
        #pragma unroll
        for (int m = 0; m < 8; ++m) af[m] = *(const bf16x8*)&Ab[aoff[m]];
        #pragma unroll
        for (int n = 0; n < 2; ++n) {
            bg[n] = *(const bf16x8*)&Gb[goff[n]];
            bu[n] = *(const bf16x8*)&Ub[goff[n]];
        }
        __builtin_amdgcn_s_setprio(1);
        #pragma unroll
        for (int m = 0; m < 8; ++m)
            #pragma unroll
            for (int n = 0; n < 2; ++n) {
                accg[m][n] = MFMA_BF16(af[m], bg[n], accg[m][n], 0, 0, 0);
                accu[m][n] = MFMA_BF16(af[m], bu[n], accu[m][n], 0, 0, 0);
            }
        __builtin_amdgcn_s_setprio(0);
        if (pf) asm volatile("s_waitcnt vmcnt(4)" ::: "memory");
        else    asm volatile("s_waitcnt vmcnt(0)" ::: "memory");
        asm volatile("s_barrier" ::: "memory");
    }
    #undef STAGE1

    ushort* outp = hb + (size_t)e * CAPP * NF + (size_t)mb * 256 * NF + nb * 128;
    #pragma unroll
    for (int m = 0; m < 8; ++m)
        #pragma unroll
        for (int n = 0; n < 2; ++n)
            #pragma unroll
            for (int r = 0; r < 4; ++r) {
                int row = wm * 128 + m * 16 + lq * 4 + r;
                int col = wn * 32 + n * 16 + lr;
                float g = accg[m][n][r], u = accu[m][n][r];
                float sg = g / (1.0f + expf(-g));
                outp[(size_t)row * NF + col] = f2bf(sg * u);
            }
}

// ---------------------------------------------------------------------------
// GEMM2: eo[e] = hb[e] @ wdT[e]^T   M=CAPP, N=NH, K=NF
// BM=256, BN=128, 8 waves (wm4 x wn2), wave out 64x64
// ---------------------------------------------------------------------------
__global__ __launch_bounds__(512, 2) void k_gemm2(
    const ushort* __restrict__ hb, const ushort* __restrict__ wdT,
    float* __restrict__ eo)
{
    __shared__ __align__(16) ushort As[4][8192];   // 64 KB
    __shared__ __align__(16) ushort Bs[4][4096];   // 32 KB

    int e = blockIdx.z, mb = blockIdx.y, nb = blockIdx.x;
    const ushort* A = hb  + (size_t)e * CAPP * NF + (size_t)mb * 256 * NF;
    const ushort* B = wdT + (size_t)e * NH * NF + (size_t)nb * 128 * NF;

    int tid = threadIdx.x, lane = tid & 63, wid = tid >> 6;
    int wm = wid >> 1, wn = wid & 1;        // wm 0..3, wn 0..1
    int lr = lane & 15, lq = lane >> 4;

    int Rg = tid >> 3;
    int ug = (tid & 7) ^ (Rg & 7);
    int sROW2 = ug >> 2;
    int sCOL  = (ug & 3) * 8;
    size_t aoffg0 = (size_t)(2 * Rg + sROW2) * NF + sCOL;
    size_t aoffg1 = (size_t)(2 * (64 + Rg) + sROW2) * NF + sCOL;
    size_t boffg  = (size_t)(2 * Rg + sROW2) * NF + sCOL;
    int aldsu0 = (wid * 8) * 64;
    int aldsu1 = (64 + wid * 8) * 64;
    int bldsu  = wid * 512;

    int aoff[4], boff[4];
    #pragma unroll
    for (int m = 0; m < 4; ++m) {
        int a = wm * 64 + m * 16 + lr;
        int Rr = a >> 1;
        int sl = (((a & 1) << 2) | lq) ^ (Rr & 7);
        aoff[m] = Rr * 64 + sl * 8;
    }
    #pragma unroll
    for (int n = 0; n < 4; ++n) {
        int nn = wn * 64 + n * 16 + lr;
        int Rr = nn >> 1;
        int sl = (((nn & 1) << 2) | lq) ^ (Rr & 7);
        boff[n] = Rr * 64 + sl * 8;
    }

    f32x4 acc[4][4] = {};

    const int NT = NF / 32;   // 64 K-tiles

    #define STAGE2(t) do { int _sl = (t) & 3; int _k0 = (t) * 32;               \
        glds16(A + aoffg0 + _k0, &As[_sl][aldsu0]);                             \
        glds16(A + aoffg1 + _k0, &As[_sl][aldsu1]);                             \
        glds16(B + boffg  + _k0, &Bs[_sl][bldsu]); } while (0)

    STAGE2(0); STAGE2(1);
    asm volatile("s_waitcnt vmcnt(3)" ::: "memory");
    asm volatile("s_barrier" ::: "memory");

    for (int t = 0; t < NT; ++t) {
        int slot = t & 3;
        bool pf = (t + 2 < NT);
        if (pf) STAGE2(t + 2);
        const ushort* Ab = &As[slot][0];
        const ushort* Bb = &Bs[slot][0];
        bf16x8 af[4], bf_[4];
        #pragma unroll
        for (int m = 0; m < 4; ++m) af[m] = *(const bf16x8*)&Ab[aoff[m]];
        #pragma unroll
        for (int n = 0; n < 4; ++n) bf_[n] = *(const bf16x8*)&Bb[boff[n]];
        __builtin_amdgcn_s_setprio(1);
        #pragma unroll
        for (int m = 0; m < 4; ++m)
            #pragma unroll
            for (int n = 0; n < 4; ++n)
                acc[m][n] = MFMA_BF16(af[m], bf_[n], acc[m][n], 0, 0, 0);
        __builtin_amdgcn_s_setprio(0);
        if (pf) asm volatile("s_waitcnt vmcnt(3)" ::: "memory");
        else    asm volatile("s_waitcnt vmcnt(0)" ::: "memory");
        asm volatile("s_barrier" ::: "memory");
    }
    #undef STAGE2

    float* outp = eo + (size_t)e * CAPP * NH + (size_t)mb * 256 * NH + nb * 128;
    #pragma unroll
    for (int m = 0; m < 4; ++m)
        #pragma unroll
        for (int n = 0; n < 4; ++n)
            #pragma unroll
            for (int r = 0; r < 4; ++r) {
                int row = wm * 64 + m * 16 + lq * 4 + r;
                int col = wn * 64 + n * 16 + lr;
                outp[(size_t)row * NH + col] = acc[m][n][r];
            }
}

// ---------------------------------------------------------------------------
// K5: out[t] = x[t] + w0*eo[e0][min(t,CAP-1)] + w1*eo[e1][min(t,CAP-1)]
// (reference gathers by CLAMPED TOKEN INDEX, not dispatch slot)
// ---------------------------------------------------------------------------
__global__ __launch_bounds__(256) void k_final(
    const float* __restrict__ x, const float* __restrict__ eo,
    const int* __restrict__ idx, const float* __restrict__ wts,
    float* __restrict__ out)
{
    int t = blockIdx.x;
    int c = (t < CAP - 1) ? t : (CAP - 1);
    int e0 = idx[2*t], e1 = idx[2*t+1];
    float w0 = wts[2*t], w1 = wts[2*t+1];
    int h = threadIdx.x * 4;
    float4 xv = *(const float4*)(x + (size_t)t * NH + h);
    float4 a = *(const float4*)(eo + ((size_t)e0 * CAPP + c) * NH + h);
    float4 b = *(const float4*)(eo + ((size_t)e1 * CAPP + c) * NH + h);
    float4 o;
    o.x = xv.x + w0 * a.x + w1 * b.x;
    o.y = xv.y + w0 * a.y + w1 * b.y;
    o.z = xv.z + w0 * a.z + w1 * b.z;
    o.w = xv.w + w0 * a.w + w1 * b.w;
    *(float4*)(out + (size_t)t * NH + h) = o;
}

// ---------------------------------------------------------------------------
extern "C" void kernel_launch(void* const* d_in, const int* in_sizes, int n_in,
                              void* d_out, int out_size, void* d_ws, size_t ws_size,
                              hipStream_t stream)
{
    const float* x     = (const float*)d_in[0];
    const float* rw    = (const float*)d_in[1];
    const float* wg    = (const float*)d_in[2];
    const float* wu    = (const float*)d_in[3];
    const float* wd    = (const float*)d_in[4];
    const float* gamma = (const float*)d_in[5];
    const float* beta  = (const float*)d_in[6];
    float* out = (float*)d_out;

    char* ws = (char*)d_ws;
    // eo overlaps tok_bf lifetime-disjointly (tok_bf dead after k_gather,
    // eo written at k_gemm2).
    float*  eo     = (float*) (ws);                 // 8*768*1024*4 = 25,165,824
    ushort* tok_bf = (ushort*)(ws);                 //  8,388,608 (aliases eo)
    ushort* xin    = (ushort*)(ws +  25165824);     // 12,582,912
    ushort* hb     = (ushort*)(ws +  37748736);     // 25,165,824
    ushort* wgT    = (ushort*)(ws +  62914560);     // 33,554,432
    ushort* wuT    = (ushort*)(ws +  96468992);     // 33,554,432
    ushort* wdT    = (ushort*)(ws + 130023424);     // 33,554,432
    int*    idx    = (int*)   (ws + 163577856);     //     32,768
    float*  wts    = (float*) (ws + 163610624);     //     32,768
    int*    sel    = (int*)   (ws + 163643392);     //     24,576
    // total ~163.7 MB

    // weight convert+transpose (one-shot, memory-bound)
    k_conv_t<<<dim3(NF / 64, NH / 128, NE), 256, 0, stream>>>(wg, wgT, NH, NF);
    k_conv_t<<<dim3(NF / 64, NH / 128, NE), 256, 0, stream>>>(wu, wuT, NH, NF);
    k_conv_t<<<dim3(NH / 64, NF / 128, NE), 256, 0, stream>>>(wd, wdT, NF, NH);

    k_ln_router<<<NT_TOK, 256, 0, stream>>>(x, rw, gamma, beta, tok_bf, idx, wts);
    k_build_sel<<<NE, 1024, 0, stream>>>(idx, sel);
    k_gather<<<NE * CAPP, 256, 0, stream>>>(sel, tok_bf, xin);
    k_gemm1<<<dim3(NF / 128, CAPP / 256, NE), 512, 0, stream>>>(xin, wgT, wuT, hb);
    k_gemm2<<<dim3(NH / 128, CAPP / 256, NE), 512, 0, stream>>>(hb, wdT, eo);
    k_final<<<NT_TOK, 256, 0, stream>>>(x, eo, idx, wts, out);
}

// Round 4
// 383.521 us; speedup vs baseline: 1.1555x; 1.1555x over previous
//
#include <hip/hip_runtime.h>
#include <hip/hip_bf16.h>

// Problem constants (from reference)
#define NE 8            // experts
#define NH 1024         // hidden
#define NF 2048         // ffn
#define NT_TOK 4096     // tokens = B*S
#define CAP 640         // ceil(1.25 * 4096 / 8); multiple of 128

typedef __bf16 bf16x8 __attribute__((ext_vector_type(8)));
typedef float f32x4 __attribute__((ext_vector_type(4)));

__device__ __forceinline__ ushort f2bf(float f) {
    union { float f; unsigned u; } v; v.f = f;
    unsigned r = (v.u + 0x7FFFu + ((v.u >> 16) & 1u)) >> 16;
    return (ushort)r;
}

// async global->LDS, 16B per lane, dest = wave-uniform base + lane*16
__device__ __forceinline__ void glds16(const ushort* g, ushort* l) {
    __builtin_amdgcn_global_load_lds((const __attribute__((address_space(1))) void*)g,
                                     (__attribute__((address_space(3))) void*)l,
                                     16, 0, 0);
}

#define MFMA_BF16 __builtin_amdgcn_mfma_f32_16x16x32_bf16

// ---------------------------------------------------------------------------
// K0: convert+transpose all 3 weight tensors.  in fp32 [R][C] -> out bf16 [C][R]
// Tile 128 r x 64 c, 256 threads. Coalesced reads (256B/row) AND writes
// (256B-contiguous uint2 rows). z: 0-7 wg, 8-15 wu, 16-23 wd. OOB blocks exit.
// ---------------------------------------------------------------------------
#define LR 132   // LDS row stride (ushorts): 264B, 8B-aligned rows

__global__ __launch_bounds__(256) void k_conv_t(
    const float* __restrict__ wg, const float* __restrict__ wu,
    const float* __restrict__ wd, ushort* __restrict__ wgT,
    ushort* __restrict__ wuT, ushort* __restrict__ wdT)
{
    int z = blockIdx.z;
    const float* in; ushort* out; int R, C;
    if (z < 8)       { in = wg + (size_t)z * NH * NF;        out = wgT + (size_t)z * NH * NF;        R = NH; C = NF; }
    else if (z < 16) { in = wu + (size_t)(z - 8) * NH * NF;  out = wuT + (size_t)(z - 8) * NH * NF;  R = NH; C = NF; }
    else             { in = wd + (size_t)(z - 16) * NF * NH; out = wdT + (size_t)(z - 16) * NF * NH; R = NF; C = NH; }
    int c0 = blockIdx.x * 64, r0 = blockIdx.y * 128;
    if (c0 >= C || r0 >= R) return;

    __shared__ __align__(16) ushort lds[64 * LR];
    int tid = threadIdx.x;
    int rr = tid >> 4;            // 0..15
    int cc = (tid & 15) * 4;      // 0..60
    #pragma unroll
    for (int it = 0; it < 8; ++it) {
        int r = it * 16 + rr;
        float4 v = *(const float4*)(in + (size_t)(r0 + r) * C + c0 + cc);
        lds[(cc + 0) * LR + r] = f2bf(v.x);
        lds[(cc + 1) * LR + r] = f2bf(v.y);
        lds[(cc + 2) * LR + r] = f2bf(v.z);
        lds[(cc + 3) * LR + r] = f2bf(v.w);
    }
    __syncthreads();
    int cb = tid >> 5;            // 0..7
    int r4 = (tid & 31) * 4;      // 0..124
    #pragma unroll
    for (int it = 0; it < 8; ++it) {
        int cI = it * 8 + cb;
        uint2 v = *(const uint2*)&lds[cI * LR + r4];
        *(uint2*)(out + (size_t)(c0 + cI) * R + r0 + r4) = v;
    }
}

// ---------------------------------------------------------------------------
// K1: per-token LayerNorm (fp32) + router logits + softmax + top-2
// ---------------------------------------------------------------------------
__global__ __launch_bounds__(256) void k_ln_router(
    const float* __restrict__ x, const float* __restrict__ rw,
    const float* __restrict__ gamma, const float* __restrict__ beta,
    ushort* __restrict__ tok_bf, int* __restrict__ idx, float* __restrict__ wts)
{
    int t = blockIdx.x, tid = threadIdx.x;
    int lane = tid & 63, wid = tid >> 6;
    const float* xp = x + (size_t)t * NH;

    float4 v = *(const float4*)(xp + tid * 4);
    float xs[4] = {v.x, v.y, v.z, v.w};
    float s = xs[0] + xs[1] + xs[2] + xs[3];
    float q = xs[0]*xs[0] + xs[1]*xs[1] + xs[2]*xs[2] + xs[3]*xs[3];

    __shared__ float rs[4], rq[4], rl[4][8];
    #pragma unroll
    for (int o = 32; o; o >>= 1) { s += __shfl_xor(s, o); q += __shfl_xor(q, o); }
    if (lane == 0) { rs[wid] = s; rq[wid] = q; }
    __syncthreads();
    float S = rs[0] + rs[1] + rs[2] + rs[3];
    float Q = rq[0] + rq[1] + rq[2] + rq[3];
    float mean = S * (1.0f / NH);
    float var  = Q * (1.0f / NH) - mean * mean;
    float rstd = 1.0f / sqrtf(var + 1e-5f);

    float le[8] = {0,0,0,0,0,0,0,0};
    ushort tb[4];
    #pragma unroll
    for (int j = 0; j < 4; ++j) {
        int h = tid * 4 + j;
        float nh = (xs[j] - mean) * rstd * gamma[h] + beta[h];
        tb[j] = f2bf(nh);
        float4 r0 = *(const float4*)(rw + h * 8);
        float4 r1 = *(const float4*)(rw + h * 8 + 4);
        le[0] += nh * r0.x; le[1] += nh * r0.y; le[2] += nh * r0.z; le[3] += nh * r0.w;
        le[4] += nh * r1.x; le[5] += nh * r1.y; le[6] += nh * r1.z; le[7] += nh * r1.w;
    }
    union { ushort s2[4]; uint2 u2; } pk;
    pk.s2[0]=tb[0]; pk.s2[1]=tb[1]; pk.s2[2]=tb[2]; pk.s2[3]=tb[3];
    *(uint2*)(tok_bf + (size_t)t * NH + tid * 4) = pk.u2;

    #pragma unroll
    for (int o = 32; o; o >>= 1)
        #pragma unroll
        for (int e = 0; e < 8; ++e) le[e] += __shfl_xor(le[e], o);
    if (lane == 0)
        #pragma unroll
        for (int e = 0; e < 8; ++e) rl[wid][e] = le[e];
    __syncthreads();

    if (tid == 0) {
        float l[8];
        #pragma unroll
        for (int e = 0; e < 8; ++e) l[e] = rl[0][e] + rl[1][e] + rl[2][e] + rl[3][e];
        float mx = l[0];
        #pragma unroll
        for (int e = 1; e < 8; ++e) mx = fmaxf(mx, l[e]);
        float p[8], den = 0.f;
        #pragma unroll
        for (int e = 0; e < 8; ++e) { p[e] = expf(l[e] - mx); den += p[e]; }
        float rden = 1.0f / den;
        #pragma unroll
        for (int e = 0; e < 8; ++e) p[e] *= rden;
        int i0 = 0; float b0 = p[0];
        #pragma unroll
        for (int e = 1; e < 8; ++e) if (p[e] > b0) { b0 = p[e]; i0 = e; }
        int i1 = (i0 == 0) ? 1 : 0; float b1 = p[i1];
        #pragma unroll
        for (int e = 0; e < 8; ++e) if (e != i0 && p[e] > b1) { b1 = p[e]; i1 = e; }
        float sw = 1.0f / (b0 + b1);
        idx[2*t] = i0; idx[2*t+1] = i1;
        wts[2*t] = b0 * sw; wts[2*t+1] = b1 * sw;
    }
}

// ---------------------------------------------------------------------------
// K2: per-expert ordered compaction (stable by token index, capacity CAP)
// ---------------------------------------------------------------------------
__global__ __launch_bounds__(1024) void k_build_sel(
    const int* __restrict__ idx, int* __restrict__ sel)
{
    int e = blockIdx.x, tid = threadIdx.x;
    int lane = tid & 63, wid = tid >> 6;
    __shared__ int wsum[16], wpre[16], sbase;
    if (tid < CAP) sel[e * CAP + tid] = -1;
    if (tid == 0) sbase = 0;
    __syncthreads();

    for (int ch = 0; ch < NT_TOK / 1024; ++ch) {
        int t = ch * 1024 + tid;
        int m = (idx[2*t] == e || idx[2*t+1] == e) ? 1 : 0;
        int v = m;
        #pragma unroll
        for (int d = 1; d < 64; d <<= 1) {
            int u = __shfl_up(v, d);
            if (lane >= d) v += u;
        }
        if (lane == 63) wsum[wid] = v;
        __syncthreads();
        if (tid < 16) {
            int ws = wsum[tid], wv = ws;
            #pragma unroll
            for (int d = 1; d < 16; d <<= 1) {
                int u = __shfl_up(wv, d);
                if (tid >= d) wv += u;
            }
            wpre[tid] = wv - ws;
        }
        __syncthreads();
        int base0 = sbase;
        int slot = base0 + wpre[wid] + v - m;
        if (m && slot < CAP) sel[e * CAP + slot] = t;
        __syncthreads();
        if (tid == 0) sbase = base0 + wpre[15] + wsum[15];
        __syncthreads();
    }
}

// ---------------------------------------------------------------------------
// K3: gather tokens into per-expert slot rows (zeros for invalid slots)
// ---------------------------------------------------------------------------
__global__ __launch_bounds__(256) void k_gather(
    const int* __restrict__ sel, const ushort* __restrict__ tok,
    ushort* __restrict__ xin)
{
    int sIdx = blockIdx.x;
    int tokid = sel[sIdx];
    uint2 v = make_uint2(0u, 0u);
    if (tokid >= 0)
        v = *(const uint2*)(tok + (size_t)tokid * NH + threadIdx.x * 4);
    *(uint2*)(xin + (size_t)sIdx * NH + threadIdx.x * 4) = v;
}

// ===========================================================================
// Pipelined grouped GEMMs: BK=32, 3 LDS slots, depth-2 prefetch, counted
// vmcnt (T4: never 0 in steady state), row-pair XOR swizzle (T2, measured 0
// conflicts in R3), setprio MFMA cluster (T5), raw s_barrier.
//
// LDS layout per slot: "LDS-row" = 128B holding TWO K-rows (a=2R, 2R+1)
//   elem (row a, 8-bf16 chunk lq) at LDS-row a>>1, 16B-slot (((a&1)<<2)|lq)^((a>>1)&7)
// Stage: glds16 linear dest (lane*16B); inverse-swizzled global source.
// ===========================================================================

// ---------------------------------------------------------------------------
// GEMM1 fused: hb[e] = silu(xin@wgT^T)*(xin@wuT^T)  M=CAP, N=NF, K=NH
// BM=128, BN=128 (gate AND up), 8 waves (2m x 4n), wave = 64r x 32c of each.
// LDS 72KB -> 2 blocks/CU; launch_bounds(512,4) caps regs at 128.
// ---------------------------------------------------------------------------
__global__ __launch_bounds__(512, 4) void k_gemm1(
    const ushort* __restrict__ xin, const ushort* __restrict__ wgT,
    const ushort* __restrict__ wuT, ushort* __restrict__ hb)
{
    __shared__ __align__(16) ushort As[3][4096];
    __shared__ __align__(16) ushort Bgs[3][4096];
    __shared__ __align__(16) ushort Bus[3][4096];

    int e = blockIdx.z, mb = blockIdx.y, nb = blockIdx.x;
    const ushort* A  = xin + (size_t)e * CAP * NH + (size_t)mb * 128 * NH;
    const ushort* Bg = wgT + (size_t)e * NF * NH + (size_t)nb * 128 * NH;
    const ushort* Bu = wuT + (size_t)e * NF * NH + (size_t)nb * 128 * NH;

    int tid = threadIdx.x, lane = tid & 63, wid = tid >> 6;
    int wm = wid >> 2, wn = wid & 3;
    int lr = lane & 15, lq = lane >> 4;

    // staging: thread covers LDS-row Rg (rows 2Rg,2Rg+1), inverse swizzle
    int Rg = tid >> 3;
    int ug = (tid & 7) ^ (Rg & 7);
    size_t goff = (size_t)(2 * Rg + (ug >> 2)) * NH + (ug & 3) * 8;
    int ldsu = tid * 8;   // ushort dest offset = wave base + lane*16B

    int aoff[4], boff[2];
    #pragma unroll
    for (int m = 0; m < 4; ++m) {
        int a = wm * 64 + m * 16 + lr;
        int Rr = a >> 1;
        int sl = (((a & 1) << 2) | lq) ^ (Rr & 7);
        aoff[m] = Rr * 64 + sl * 8;
    }
    #pragma unroll
    for (int n = 0; n < 2; ++n) {
        int c = wn * 32 + n * 16 + lr;
        int Rr = c >> 1;
        int sl = (((c & 1) << 2) | lq) ^ (Rr & 7);
        boff[n] = Rr * 64 + sl * 8;
    }

    f32x4 accg[4][2] = {}; f32x4 accu[4][2] = {};
    const int NT = NH / 32;   // 32 K-tiles

    #define STG1(t, s) do { size_t _k = (size_t)(t) * 32;                       \
        glds16(A  + goff + _k, &As[s][ldsu]);                                   \
        glds16(Bg + goff + _k, &Bgs[s][ldsu]);                                  \
        glds16(Bu + goff + _k, &Bus[s][ldsu]); } while (0)

    STG1(0, 0); STG1(1, 1);
    asm volatile("s_waitcnt vmcnt(3)" ::: "memory");
    asm volatile("s_barrier" ::: "memory");

    int sl_c = 0, sl_p = 2;
    for (int t = 0; t < NT; ++t) {
        bool pf = (t + 2 < NT);
        if (pf) STG1(t + 2, sl_p);
        const ushort* Ab = &As[sl_c][0];
        const ushort* Gb = &Bgs[sl_c][0];
        const ushort* Ub = &Bus[sl_c][0];
        bf16x8 af[4], bg[2], bu[2];
        #pragma unroll
        for (int m = 0; m < 4; ++m) af[m] = *(const bf16x8*)&Ab[aoff[m]];
        #pragma unroll
        for (int n = 0; n < 2; ++n) {
            bg[n] = *(const bf16x8*)&Gb[boff[n]];
            bu[n] = *(const bf16x8*)&Ub[boff[n]];
        }
        __builtin_amdgcn_s_setprio(1);
        #pragma unroll
        for (int m = 0; m < 4; ++m)
            #pragma unroll
            for (int n = 0; n < 2; ++n) {
                accg[m][n] = MFMA_BF16(af[m], bg[n], accg[m][n], 0, 0, 0);
                accu[m][n] = MFMA_BF16(af[m], bu[n], accu[m][n], 0, 0, 0);
            }
        __builtin_amdgcn_s_setprio(0);
        if (pf) asm volatile("s_waitcnt vmcnt(3)" ::: "memory");
        else    asm volatile("s_waitcnt vmcnt(0)" ::: "memory");
        asm volatile("s_barrier" ::: "memory");
        sl_c = (sl_c == 2) ? 0 : sl_c + 1;
        sl_p = (sl_p == 2) ? 0 : sl_p + 1;
    }
    #undef STG1

    ushort* outp = hb + (size_t)e * CAP * NF + (size_t)mb * 128 * NF + nb * 128;
    #pragma unroll
    for (int m = 0; m < 4; ++m)
        #pragma unroll
        for (int n = 0; n < 2; ++n)
            #pragma unroll
            for (int r = 0; r < 4; ++r) {
                int row = wm * 64 + m * 16 + lq * 4 + r;
                int col = wn * 32 + n * 16 + lr;
                float g = accg[m][n][r], u = accu[m][n][r];
                float sg = g / (1.0f + expf(-g));
                outp[(size_t)row * NF + col] = f2bf(sg * u);
            }
}

// ---------------------------------------------------------------------------
// GEMM2: eo[e] = hb[e] @ wdT[e]^T   M=CAP, N=NH, K=NF
// BM=128, BN=128, 256 thr (4 waves 2x2, wave 64x64). LDS 48KB -> 3 blocks/CU.
// ---------------------------------------------------------------------------
__global__ __launch_bounds__(256, 4) void k_gemm2(
    const ushort* __restrict__ hb, const ushort* __restrict__ wdT,
    float* __restrict__ eo)
{
    __shared__ __align__(16) ushort As[3][4096];
    __shared__ __align__(16) ushort Bs[3][4096];

    int e = blockIdx.z, mb = blockIdx.y, nb = blockIdx.x;
    const ushort* A = hb  + (size_t)e * CAP * NF + (size_t)mb * 128 * NF;
    const ushort* B = wdT + (size_t)e * NH * NF + (size_t)nb * 128 * NF;

    int tid = threadIdx.x, lane = tid & 63, wid = tid >> 6;
    int wm = wid >> 1, wn = wid & 1;
    int lr = lane & 15, lq = lane >> 4;

    // staging: 2 issues per matrix; issue j covers LDS-rows j*32 + (tid>>3)
    int Rg = tid >> 3;                    // 0..31
    int ug = (tid & 7) ^ (Rg & 7);        // (j*32) % 8 == 0 -> same u both issues
    int sROW2 = ug >> 2, sCOL = (ug & 3) * 8;
    size_t goff0 = (size_t)(2 * Rg + sROW2) * NF + sCOL;
    size_t goff1 = (size_t)(2 * (32 + Rg) + sROW2) * NF + sCOL;
    int ldsu = tid * 8;

    int aoff[4], boff[4];
    #pragma unroll
    for (int m = 0; m < 4; ++m) {
        int a = wm * 64 + m * 16 + lr;
        int Rr = a >> 1;
        int sl = (((a & 1) << 2) | lq) ^ (Rr & 7);
        aoff[m] = Rr * 64 + sl * 8;
    }
    #pragma unroll
    for (int n = 0; n < 4; ++n) {
        int c = wn * 64 + n * 16 + lr;
        int Rr = c >> 1;
        int sl = (((c & 1) << 2) | lq) ^ (Rr & 7);
        boff[n] = Rr * 64 + sl * 8;
    }

    f32x4 acc[4][4] = {};
    const int NT = NF / 32;   // 64 K-tiles

    #define STG2(t, s) do { size_t _k = (size_t)(t) * 32;                       \
        glds16(A + goff0 + _k, &As[s][ldsu]);                                   \
        glds16(A + goff1 + _k, &As[s][2048 + ldsu]);                            \
        glds16(B + goff0 + _k, &Bs[s][ldsu]);                                   \
        glds16(B + goff1 + _k, &Bs[s][2048 + ldsu]); } while (0)

    STG2(0, 0); STG2(1, 1);
    asm volatile("s_waitcnt vmcnt(4)" ::: "memory");
    asm volatile("s_barrier" ::: "memory");

    int sl_c = 0, sl_p = 2;
    for (int t = 0; t < NT; ++t) {
        bool pf = (t + 2 < NT);
        if (pf) STG2(t + 2, sl_p);
        const ushort* Ab = &As[sl_c][0];
        const ushort* Bb = &Bs[sl_c][0];
        bf16x8 af[4], bf_[4];
        #pragma unroll
        for (int m = 0; m < 4; ++m) af[m] = *(const bf16x8*)&Ab[aoff[m]];
        #pragma unroll
        for (int n = 0; n < 4; ++n) bf_[n] = *(const bf16x8*)&Bb[boff[n]];
        __builtin_amdgcn_s_setprio(1);
        #pragma unroll
        for (int m = 0; m < 4; ++m)
            #pragma unroll
            for (int n = 0; n < 4; ++n)
                acc[m][n] = MFMA_BF16(af[m], bf_[n], acc[m][n], 0, 0, 0);
        __builtin_amdgcn_s_setprio(0);
        if (pf) asm volatile("s_waitcnt vmcnt(4)" ::: "memory");
        else    asm volatile("s_waitcnt vmcnt(0)" ::: "memory");
        asm volatile("s_barrier" ::: "memory");
        sl_c = (sl_c == 2) ? 0 : sl_c + 1;
        sl_p = (sl_p == 2) ? 0 : sl_p + 1;
    }
    #undef STG2

    float* outp = eo + (size_t)e * CAP * NH + (size_t)mb * 128 * NH + nb * 128;
    #pragma unroll
    for (int m = 0; m < 4; ++m)
        #pragma unroll
        for (int n = 0; n < 4; ++n)
            #pragma unroll
            for (int r = 0; r < 4; ++r) {
                int row = wm * 64 + m * 16 + lq * 4 + r;
                int col = wn * 64 + n * 16 + lr;
                outp[(size_t)row * NH + col] = acc[m][n][r];
            }
}

// ---------------------------------------------------------------------------
// K5: out[t] = x[t] + w0*eo[e0][min(t,CAP-1)] + w1*eo[e1][min(t,CAP-1)]
// (reference gathers by CLAMPED TOKEN INDEX, not dispatch slot)
// ---------------------------------------------------------------------------
__global__ __launch_bounds__(256) void k_final(
    const float* __restrict__ x, const float* __restrict__ eo,
    const int* __restrict__ idx, const float* __restrict__ wts,
    float* __restrict__ out)
{
    int t = blockIdx.x;
    int c = (t < CAP - 1) ? t : (CAP - 1);
    int e0 = idx[2*t], e1 = idx[2*t+1];
    float w0 = wts[2*t], w1 = wts[2*t+1];
    int h = threadIdx.x * 4;
    float4 xv = *(const float4*)(x + (size_t)t * NH + h);
    float4 a = *(const float4*)(eo + ((size_t)e0 * CAP + c) * NH + h);
    float4 b = *(const float4*)(eo + ((size_t)e1 * CAP + c) * NH + h);
    float4 o;
    o.x = xv.x + w0 * a.x + w1 * b.x;
    o.y = xv.y + w0 * a.y + w1 * b.y;
    o.z = xv.z + w0 * a.z + w1 * b.z;
    o.w = xv.w + w0 * a.w + w1 * b.w;
    *(float4*)(out + (size_t)t * NH + h) = o;
}

// ---------------------------------------------------------------------------
extern "C" void kernel_launch(void* const* d_in, const int* in_sizes, int n_in,
                              void* d_out, int out_size, void* d_ws, size_t ws_size,
                              hipStream_t stream)
{
    const float* x     = (const float*)d_in[0];
    const float* rw    = (const float*)d_in[1];
    const float* wg    = (const float*)d_in[2];
    const float* wu    = (const float*)d_in[3];
    const float* wd    = (const float*)d_in[4];
    const float* gamma = (const float*)d_in[5];
    const float* beta  = (const float*)d_in[6];
    float* out = (float*)d_out;

    char* ws = (char*)d_ws;
    // eo (written in gemm2) aliases tok_bf (dead after k_gather)
    float*  eo     = (float*) (ws);                 // 8*640*1024*4 = 20,971,520
    ushort* tok_bf = (ushort*)(ws);                 //  8,388,608 (alias)
    ushort* xin    = (ushort*)(ws +  20971520);     // 10,485,760
    ushort* hb     = (ushort*)(ws +  31457280);     // 20,971,520
    ushort* wgT    = (ushort*)(ws +  52428800);     // 33,554,432
    ushort* wuT    = (ushort*)(ws +  85983232);     // 33,554,432
    ushort* wdT    = (ushort*)(ws + 119537664);     // 33,554,432
    int*    idx    = (int*)   (ws + 153092096);     //     32,768
    float*  wts    = (float*) (ws + 153124864);     //     32,768
    int*    sel    = (int*)   (ws + 153157632);     //     20,480
    // total ~153.2 MB

    // weight convert+transpose, all three tensors in one dispatch
    k_conv_t<<<dim3(32, 16, 24), 256, 0, stream>>>(wg, wu, wd, wgT, wuT, wdT);

    k_ln_router<<<NT_TOK, 256, 0, stream>>>(x, rw, gamma, beta, tok_bf, idx, wts);
    k_build_sel<<<NE, 1024, 0, stream>>>(idx, sel);
    k_gather<<<NE * CAP, 256, 0, stream>>>(sel, tok_bf, xin);
    k_gemm1<<<dim3(NF / 128, CAP / 128, NE), 512, 0, stream>>>(xin, wgT, wuT, hb);
    k_gemm2<<<dim3(NH / 128, CAP / 128, NE), 256, 0, stream>>>(hb, wdT, eo);
    k_final<<<NT_TOK, 256, 0, stream>>>(x, eo, idx, wts, out);
}